// Round 1
// baseline (1598.282 us; speedup 1.0000x reference)
//
#include <hip/hip_runtime.h>

#define NN 100000
#define NE 3200000
#define NG 1000
#define DIM 128
#define OUTD 64
#define NLAYER 3
#define BN_EPS 1e-5f

// ---------------- CSR build ----------------
__global__ void k_hist(const int* __restrict__ dst, int* __restrict__ cnt) {
    int e = blockIdx.x * blockDim.x + threadIdx.x;
    if (e < NE) atomicAdd(&cnt[dst[e]], 1);
}

#define SCAN_CHUNK 1024  // 256 threads * 4 elements

__global__ __launch_bounds__(256) void k_scan1(const int* __restrict__ cnt, int* __restrict__ bsum) {
    __shared__ int sh[256];
    int base = blockIdx.x * SCAN_CHUNK + threadIdx.x * 4;
    int s = 0;
#pragma unroll
    for (int j = 0; j < 4; ++j) { int i = base + j; if (i < NN) s += cnt[i]; }
    sh[threadIdx.x] = s;
    __syncthreads();
    if (threadIdx.x == 0) {
        int t = 0;
        for (int i = 0; i < 256; ++i) t += sh[i];
        bsum[blockIdx.x] = t;
    }
}

__global__ void k_scan2(const int* __restrict__ bsum, int* __restrict__ boff, int nb, int* __restrict__ off_last) {
    int t = 0;
    for (int i = 0; i < nb; ++i) { boff[i] = t; t += bsum[i]; }
    *off_last = t;
}

__global__ __launch_bounds__(256) void k_scan3(const int* __restrict__ cnt, const int* __restrict__ boff, int* __restrict__ off) {
    __shared__ int sh[256];
    __shared__ int shoff[256];
    int base = blockIdx.x * SCAN_CHUNK + threadIdx.x * 4;
    int c[4];
    int s = 0;
#pragma unroll
    for (int j = 0; j < 4; ++j) { int i = base + j; c[j] = (i < NN) ? cnt[i] : 0; s += c[j]; }
    sh[threadIdx.x] = s;
    __syncthreads();
    if (threadIdx.x == 0) {
        int t = 0;
        for (int i = 0; i < 256; ++i) { shoff[i] = t; t += sh[i]; }
    }
    __syncthreads();
    int run = boff[blockIdx.x] + shoff[threadIdx.x];
#pragma unroll
    for (int j = 0; j < 4; ++j) {
        int i = base + j;
        if (i < NN) off[i] = run;
        run += c[j];
    }
}

__global__ void k_scatter(const int* __restrict__ src, const int* __restrict__ dst,
                          int* __restrict__ cursor, int* __restrict__ srcs) {
    int e = blockIdx.x * blockDim.x + threadIdx.x;
    if (e < NE) {
        int d = dst[e];
        int pos = atomicAdd(&cursor[d], 1);
        srcs[pos] = src[e];
    }
}

__global__ void k_starts(const int* __restrict__ batch, int* __restrict__ starts) {
    int g = blockIdx.x * blockDim.x + threadIdx.x;
    if (g > NG) return;
    int lo = 0, hi = NN;
    while (lo < hi) {
        int mid = (lo + hi) >> 1;
        if (batch[mid] < g) lo = mid + 1; else hi = mid;
    }
    starts[g] = lo;
}

// ---------------- Aggregation: h0 = x + sum_{j->i} x_j ----------------
__global__ __launch_bounds__(256) void k_agg(const float* __restrict__ x, const int* __restrict__ off,
                                             const int* __restrict__ srcs, float* __restrict__ h0) {
    int wid = threadIdx.x >> 6;
    int lane = threadIdx.x & 63;
    int node = blockIdx.x * 4 + wid;
    if (node >= NN) return;
    const float2* x2 = (const float2*)x;
    float2 acc = x2[(size_t)node * 64 + lane];
    int e = off[node], eend = off[node + 1];
    for (; e + 1 < eend; e += 2) {
        int s0 = srcs[e], s1 = srcs[e + 1];
        float2 v0 = x2[(size_t)s0 * 64 + lane];
        float2 v1 = x2[(size_t)s1 * 64 + lane];
        acc.x += v0.x + v1.x;
        acc.y += v0.y + v1.y;
    }
    if (e < eend) {
        int s0 = srcs[e];
        float2 v0 = x2[(size_t)s0 * 64 + lane];
        acc.x += v0.x;
        acc.y += v0.y;
    }
    ((float2*)h0)[(size_t)node * 64 + lane] = acc;
}

// ---------------- fp32 GEMM: C[M,128] = H[M,128] @ W[128,128] + bias (opt ReLU) ----------------
__global__ __launch_bounds__(256) void k_gemm(const float* __restrict__ H, const float* __restrict__ W,
                                              const float* __restrict__ bias, float* __restrict__ C,
                                              int relu) {
    __shared__ float Hs[32][68];   // [k][row], padded: row stride 272B = 16B-aligned
    __shared__ float Ws[32][128];  // [k][col]
    int m0 = blockIdx.x * 64;
    int tid = threadIdx.x;
    int tx = tid & 15, ty = tid >> 4;
    int r0 = ty * 4, c0 = tx * 8;

    float acc[4][8];
#pragma unroll
    for (int r = 0; r < 4; ++r)
#pragma unroll
        for (int c = 0; c < 8; ++c) acc[r][c] = 0.f;

    for (int kc = 0; kc < 128; kc += 32) {
        // H chunk: 64 rows x 32 cols = 512 float4
#pragma unroll
        for (int l = 0; l < 2; ++l) {
            int f = tid + 256 * l;
            int row = f >> 3, kq = f & 7;
            int grow = m0 + row;
            if (grow >= NN) grow = NN - 1;
            float4 v = *(const float4*)&H[(size_t)grow * 128 + kc + kq * 4];
            Hs[kq * 4 + 0][row] = v.x;
            Hs[kq * 4 + 1][row] = v.y;
            Hs[kq * 4 + 2][row] = v.z;
            Hs[kq * 4 + 3][row] = v.w;
        }
        // W chunk: 32 rows x 128 cols = 1024 float4
#pragma unroll
        for (int l = 0; l < 4; ++l) {
            int f = tid + 256 * l;
            int kr = f >> 5, cq = f & 31;
            *(float4*)&Ws[kr][cq * 4] = *(const float4*)&W[(size_t)(kc + kr) * 128 + cq * 4];
        }
        __syncthreads();
#pragma unroll 8
        for (int k = 0; k < 32; ++k) {
            float4 a = *(const float4*)&Hs[k][r0];
            float4 bq0 = *(const float4*)&Ws[k][c0];
            float4 bq1 = *(const float4*)&Ws[k][c0 + 4];
            float av[4] = {a.x, a.y, a.z, a.w};
            float bv[8] = {bq0.x, bq0.y, bq0.z, bq0.w, bq1.x, bq1.y, bq1.z, bq1.w};
#pragma unroll
            for (int r = 0; r < 4; ++r)
#pragma unroll
                for (int c = 0; c < 8; ++c)
                    acc[r][c] = fmaf(av[r], bv[c], acc[r][c]);
        }
        __syncthreads();
    }

    float bb[8];
#pragma unroll
    for (int j = 0; j < 8; ++j) bb[j] = bias[c0 + j];

#pragma unroll
    for (int r = 0; r < 4; ++r) {
        int grow = m0 + r0 + r;
        if (grow >= NN) continue;
        float o[8];
#pragma unroll
        for (int c = 0; c < 8; ++c) {
            o[c] = acc[r][c] + bb[c];
            if (relu) o[c] = fmaxf(o[c], 0.f);
        }
        float4 o0 = {o[0], o[1], o[2], o[3]};
        float4 o1 = {o[4], o[5], o[6], o[7]};
        *(float4*)&C[(size_t)grow * 128 + c0] = o0;
        *(float4*)&C[(size_t)grow * 128 + c0 + 4] = o1;
    }
}

// ---------------- BatchNorm column stats ----------------
__global__ __launch_bounds__(256) void k_colstats(const float* __restrict__ H,
                                                  float* __restrict__ gsum, float* __restrict__ gsq) {
    __shared__ float ls[128];
    __shared__ float lq[128];
    if (threadIdx.x < 128) { ls[threadIdx.x] = 0.f; lq[threadIdx.x] = 0.f; }
    __syncthreads();
    int cg = threadIdx.x & 31;  // column quad id
    int rs = threadIdx.x >> 5;  // 0..7
    float4 s = {0, 0, 0, 0}, q = {0, 0, 0, 0};
    for (int r = blockIdx.x * 8 + rs; r < NN; r += gridDim.x * 8) {
        float4 v = *(const float4*)&H[(size_t)r * 128 + cg * 4];
        s.x += v.x; s.y += v.y; s.z += v.z; s.w += v.w;
        q.x += v.x * v.x; q.y += v.y * v.y; q.z += v.z * v.z; q.w += v.w * v.w;
    }
    atomicAdd(&ls[cg * 4 + 0], s.x);
    atomicAdd(&ls[cg * 4 + 1], s.y);
    atomicAdd(&ls[cg * 4 + 2], s.z);
    atomicAdd(&ls[cg * 4 + 3], s.w);
    atomicAdd(&lq[cg * 4 + 0], q.x);
    atomicAdd(&lq[cg * 4 + 1], q.y);
    atomicAdd(&lq[cg * 4 + 2], q.z);
    atomicAdd(&lq[cg * 4 + 3], q.w);
    __syncthreads();
    if (threadIdx.x < 128) {
        atomicAdd(&gsum[threadIdx.x], ls[threadIdx.x]);
        atomicAdd(&gsq[threadIdx.x], lq[threadIdx.x]);
    }
}

// ---------------- BN apply + ReLU (in place) ----------------
__global__ __launch_bounds__(256) void k_bnrelu(float* __restrict__ H,
                                                const float* __restrict__ gsum, const float* __restrict__ gsq,
                                                const float* __restrict__ gamma, const float* __restrict__ beta) {
    int i4 = blockIdx.x * blockDim.x + threadIdx.x;  // float4 index, NN*32 total
    if (i4 >= NN * 32) return;
    int cq = i4 & 31;
    float4 v = ((float4*)H)[i4];
    float4 sv = ((const float4*)gsum)[cq];
    float4 qv = ((const float4*)gsq)[cq];
    float4 gv = ((const float4*)gamma)[cq];
    float4 bv = ((const float4*)beta)[cq];
    const float inv = 1.0f / (float)NN;
    float mu, var, sc;
    mu = sv.x * inv; var = qv.x * inv - mu * mu; sc = gv.x * rsqrtf(var + BN_EPS);
    v.x = fmaxf((v.x - mu) * sc + bv.x, 0.f);
    mu = sv.y * inv; var = qv.y * inv - mu * mu; sc = gv.y * rsqrtf(var + BN_EPS);
    v.y = fmaxf((v.y - mu) * sc + bv.y, 0.f);
    mu = sv.z * inv; var = qv.z * inv - mu * mu; sc = gv.z * rsqrtf(var + BN_EPS);
    v.z = fmaxf((v.z - mu) * sc + bv.z, 0.f);
    mu = sv.w * inv; var = qv.w * inv - mu * mu; sc = gv.w * rsqrtf(var + BN_EPS);
    v.w = fmaxf((v.w - mu) * sc + bv.w, 0.f);
    ((float4*)H)[i4] = v;
}

// ---------------- per-graph mean pool ----------------
__global__ __launch_bounds__(256) void k_pool(const float* __restrict__ X, const int* __restrict__ starts,
                                              float* __restrict__ pooled) {
    int g = blockIdx.x;
    int s = starts[g], e = starts[g + 1];
    int w = threadIdx.x >> 6, lane = threadIdx.x & 63;
    const float2* x2 = (const float2*)X;
    float2 acc = {0.f, 0.f};
    for (int r = s + w; r < e; r += 4) {
        float2 v = x2[(size_t)r * 64 + lane];
        acc.x += v.x;
        acc.y += v.y;
    }
    __shared__ float2 red[4][64];
    red[w][lane] = acc;
    __syncthreads();
    if (w == 0) {
        float2 a = red[0][lane], b = red[1][lane], c = red[2][lane], d = red[3][lane];
        float cnt = (float)((e - s) > 0 ? (e - s) : 1);
        float2 o;
        o.x = (a.x + b.x + c.x + d.x) / cnt;
        o.y = (a.y + b.y + c.y + d.y) / cnt;
        ((float2*)pooled)[(size_t)g * 64 + lane] = o;
    }
}

// ---------------- final linear: out[G,64] = pooled[G,128] @ lin_w[128,64] + lin_b ----------------
__global__ __launch_bounds__(64) void k_final(const float* __restrict__ pooled, const float* __restrict__ lw,
                                              const float* __restrict__ lb, float* __restrict__ out) {
    int g = blockIdx.x, o = threadIdx.x;
    float acc = lb[o];
    const float* p = &pooled[(size_t)g * 128];
#pragma unroll 8
    for (int k = 0; k < 128; ++k) acc = fmaf(p[k], lw[k * 64 + o], acc);
    out[(size_t)g * 64 + o] = acc;
}

extern "C" void kernel_launch(void* const* d_in, const int* in_sizes, int n_in,
                              void* d_out, int out_size, void* d_ws, size_t ws_size,
                              hipStream_t stream) {
    const float* x = (const float*)d_in[0];
    const int* ei = (const int*)d_in[1];
    const int* src = ei;
    const int* dst = ei + NE;
    const int* batch = (const int*)d_in[2];
    const float* W1 = (const float*)d_in[3];
    const float* b1 = (const float*)d_in[4];
    const float* W2 = (const float*)d_in[5];
    const float* b2 = (const float*)d_in[6];
    const float* gamma = (const float*)d_in[7];
    const float* beta = (const float*)d_in[8];
    const float* lw = (const float*)d_in[9];
    const float* lb = (const float*)d_in[10];
    float* out = (float*)d_out;

    char* p = (char*)d_ws;
    auto alloc = [&](size_t bytes) {
        char* r = p;
        p += (bytes + 511) & ~(size_t)511;
        return r;
    };
    float* A = (float*)alloc((size_t)NN * DIM * 4);
    float* B = (float*)alloc((size_t)NN * DIM * 4);
    float* Cb = (float*)alloc((size_t)NN * DIM * 4);
    int* srcs = (int*)alloc((size_t)NE * 4);
    int* off = (int*)alloc((size_t)(NN + 1) * 4);
    int* cursor = (int*)alloc((size_t)(NN + 1) * 4);
    int* bsum = (int*)alloc(128 * 4);
    int* boff = (int*)alloc(128 * 4);
    float* gsum = (float*)alloc(DIM * 4);
    float* gsq = (float*)alloc(DIM * 4);
    int* starts = (int*)alloc((NG + 1) * 4);
    float* pooled = (float*)alloc((size_t)NG * DIM * 4);

    // ---- CSR build (dst-sorted src lists), once per call
    hipMemsetAsync(cursor, 0, (size_t)NN * 4, stream);
    k_hist<<<NE / 256, 256, 0, stream>>>(dst, cursor);
    int nb = (NN + SCAN_CHUNK - 1) / SCAN_CHUNK;  // 98
    k_scan1<<<nb, 256, 0, stream>>>(cursor, bsum);
    k_scan2<<<1, 1, 0, stream>>>(bsum, boff, nb, off + NN);
    k_scan3<<<nb, 256, 0, stream>>>(cursor, boff, off);
    hipMemcpyAsync(cursor, off, (size_t)NN * 4, hipMemcpyDeviceToDevice, stream);
    k_scatter<<<NE / 256, 256, 0, stream>>>(src, dst, cursor, srcs);
    k_starts<<<(NG + 1 + 255) / 256, 256, 0, stream>>>(batch, starts);

    // ---- 3 GIN layers
    const float* xin[3] = {x, A, B};
    float* h0b[3] = {A, B, A};
    float* h1b[3] = {B, Cb, Cb};
    float* h2b[3] = {A, B, A};
    for (int l = 0; l < NLAYER; ++l) {
        k_agg<<<NN / 4, 256, 0, stream>>>(xin[l], off, srcs, h0b[l]);
        k_gemm<<<(NN + 63) / 64, 256, 0, stream>>>(h0b[l], W1 + (size_t)l * DIM * DIM, b1 + l * DIM, h1b[l], 1);
        k_gemm<<<(NN + 63) / 64, 256, 0, stream>>>(h1b[l], W2 + (size_t)l * DIM * DIM, b2 + l * DIM, h2b[l], 0);
        hipMemsetAsync(gsum, 0, DIM * 4, stream);
        hipMemsetAsync(gsq, 0, DIM * 4, stream);
        k_colstats<<<1024, 256, 0, stream>>>(h2b[l], gsum, gsq);
        k_bnrelu<<<(NN * 32 + 255) / 256, 256, 0, stream>>>(h2b[l], gsum, gsq, gamma + l * DIM, beta + l * DIM);
    }

    // ---- pool + final linear
    k_pool<<<NG, 256, 0, stream>>>(h2b[2], starts, pooled);
    k_final<<<NG, 64, 0, stream>>>(pooled, lw, lb, out);
}

// Round 2
// 1214.492 us; speedup vs baseline: 1.3160x; 1.3160x over previous
//
#include <hip/hip_runtime.h>

#define NN 100000
#define NE 3200000
#define NG 1000
#define DIM 128
#define OUTD 64
#define NLAYER 3
#define BN_EPS 1e-5f

typedef __attribute__((ext_vector_type(8))) short bf16x8;
typedef __attribute__((ext_vector_type(4))) float f32x4;

__device__ __forceinline__ float bflo(unsigned int u) { return __builtin_bit_cast(float, u << 16); }
__device__ __forceinline__ float bfhi(unsigned int u) { return __builtin_bit_cast(float, u & 0xffff0000u); }
__device__ __forceinline__ unsigned short f2bf(float f) {
    unsigned int x = __builtin_bit_cast(unsigned int, f);
    return (unsigned short)((x + 0x7fffu + ((x >> 16) & 1u)) >> 16);
}

// ---------------- CSR build ----------------
__global__ void k_hist(const int* __restrict__ dst, int* __restrict__ cnt) {
    int e = blockIdx.x * blockDim.x + threadIdx.x;
    if (e < NE) atomicAdd(&cnt[dst[e]], 1);
}

#define SCAN_CHUNK 1024

__global__ __launch_bounds__(256) void k_scan1(const int* __restrict__ cnt, int* __restrict__ bsum) {
    __shared__ int sh[256];
    int base = blockIdx.x * SCAN_CHUNK + threadIdx.x * 4;
    int s = 0;
#pragma unroll
    for (int j = 0; j < 4; ++j) { int i = base + j; if (i < NN) s += cnt[i]; }
    sh[threadIdx.x] = s;
    __syncthreads();
    if (threadIdx.x == 0) {
        int t = 0;
        for (int i = 0; i < 256; ++i) t += sh[i];
        bsum[blockIdx.x] = t;
    }
}

__global__ void k_scan2(const int* __restrict__ bsum, int* __restrict__ boff, int nb, int* __restrict__ off_last) {
    int t = 0;
    for (int i = 0; i < nb; ++i) { boff[i] = t; t += bsum[i]; }
    *off_last = t;
}

__global__ __launch_bounds__(256) void k_scan3(const int* __restrict__ cnt, const int* __restrict__ boff, int* __restrict__ off) {
    __shared__ int sh[256];
    __shared__ int shoff[256];
    int base = blockIdx.x * SCAN_CHUNK + threadIdx.x * 4;
    int c[4];
    int s = 0;
#pragma unroll
    for (int j = 0; j < 4; ++j) { int i = base + j; c[j] = (i < NN) ? cnt[i] : 0; s += c[j]; }
    sh[threadIdx.x] = s;
    __syncthreads();
    if (threadIdx.x == 0) {
        int t = 0;
        for (int i = 0; i < 256; ++i) { shoff[i] = t; t += sh[i]; }
    }
    __syncthreads();
    int run = boff[blockIdx.x] + shoff[threadIdx.x];
#pragma unroll
    for (int j = 0; j < 4; ++j) {
        int i = base + j;
        if (i < NN) off[i] = run;
        run += c[j];
    }
}

__global__ void k_scatter(const int* __restrict__ src, const int* __restrict__ dst,
                          int* __restrict__ cursor, int* __restrict__ srcs) {
    int e = blockIdx.x * blockDim.x + threadIdx.x;
    if (e < NE) {
        int d = dst[e];
        int pos = atomicAdd(&cursor[d], 1);
        srcs[pos] = src[e];
    }
}

__global__ void k_starts(const int* __restrict__ batch, int* __restrict__ starts) {
    int g = blockIdx.x * blockDim.x + threadIdx.x;
    if (g > NG) return;
    int lo = 0, hi = NN;
    while (lo < hi) {
        int mid = (lo + hi) >> 1;
        if (batch[mid] < g) lo = mid + 1; else hi = mid;
    }
    starts[g] = lo;
}

// ---------------- prep: fp32 -> bf16 ----------------
__global__ __launch_bounds__(256) void k_prep_x(const float* __restrict__ x, unsigned short* __restrict__ xb) {
    int i = blockIdx.x * 256 + threadIdx.x;  // uint4 out index, NN*16 total
    if (i >= NN * 16) return;
    const float4* xp = (const float4*)x;
    float4 a = xp[(size_t)i * 2], b = xp[(size_t)i * 2 + 1];
    uint4 o;
    o.x = (unsigned int)f2bf(a.x) | ((unsigned int)f2bf(a.y) << 16);
    o.y = (unsigned int)f2bf(a.z) | ((unsigned int)f2bf(a.w) << 16);
    o.z = (unsigned int)f2bf(b.x) | ((unsigned int)f2bf(b.y) << 16);
    o.w = (unsigned int)f2bf(b.z) | ((unsigned int)f2bf(b.w) << 16);
    ((uint4*)xb)[i] = o;
}

// W[k][c] fp32 -> Wt[c][k] bf16, XOR-swizzled 16B chunks (chunk ^= c&7)
__global__ __launch_bounds__(256) void k_prep_w(const float* __restrict__ W1, const float* __restrict__ W2,
                                                unsigned short* __restrict__ Wt) {
    int i = blockIdx.x * 256 + threadIdx.x;  // 6*16384
    if (i >= 6 * 16384) return;
    int w = i >> 14, r = i & 16383;
    int k = r >> 7, c = r & 127;
    const float* Ws = (w < 3) ? (W1 + (size_t)w * 16384) : (W2 + (size_t)(w - 3) * 16384);
    float v = Ws[r];
    int dst = (c << 7) + ((((k >> 3) ^ (c & 7)) << 3)) + (k & 7);
    Wt[((size_t)w << 14) + dst] = f2bf(v);
}

// ---------------- Aggregation (bf16): h0 = x + sum_{j->i} x_j ----------------
__global__ __launch_bounds__(256) void k_agg(const unsigned short* __restrict__ x, const int* __restrict__ off,
                                             const int* __restrict__ srcs, unsigned short* __restrict__ h0) {
    int wid = threadIdx.x >> 6;
    int lane = threadIdx.x & 63;
    int node = blockIdx.x * 4 + wid;
    if (node >= NN) return;
    const unsigned int* x1 = (const unsigned int*)x;
    unsigned int u = x1[(size_t)node * 64 + lane];
    float ax = bflo(u), ay = bfhi(u);
    int e = off[node], eend = off[node + 1];
    for (; e + 1 < eend; e += 2) {
        int s0 = srcs[e], s1 = srcs[e + 1];
        unsigned int u0 = x1[(size_t)s0 * 64 + lane];
        unsigned int u1 = x1[(size_t)s1 * 64 + lane];
        ax += bflo(u0) + bflo(u1);
        ay += bfhi(u0) + bfhi(u1);
    }
    if (e < eend) {
        unsigned int u0 = x1[(size_t)srcs[e] * 64 + lane];
        ax += bflo(u0);
        ay += bfhi(u0);
    }
    ((unsigned int*)h0)[(size_t)node * 64 + lane] = (unsigned int)f2bf(ax) | ((unsigned int)f2bf(ay) << 16);
}

// ---------------- MFMA bf16 GEMM: C[M,128] = H[M,128]@W[128,128] + bias ----------------
template <int RELU, int STATS>
__global__ __launch_bounds__(256) void k_gemm(const unsigned short* __restrict__ H,
                                              const unsigned short* __restrict__ Wt,
                                              const float* __restrict__ bias,
                                              unsigned short* __restrict__ C,
                                              float* __restrict__ gsum, float* __restrict__ gsq) {
    __shared__ unsigned short Wl[16384];  // 32KB swizzled Wt image; reused as output stage
    __shared__ float lsum[128], lsq[128];
    int tid = threadIdx.x;
    {
        const uint4* s4 = (const uint4*)Wt;
        uint4* d4 = (uint4*)Wl;
#pragma unroll
        for (int i = 0; i < 8; ++i) d4[tid + 256 * i] = s4[tid + 256 * i];
    }
    if (STATS && tid < 128) { lsum[tid] = 0.f; lsq[tid] = 0.f; }
    __syncthreads();

    int w = tid >> 6, l = tid & 63;
    int lr = l & 15, lg = l >> 4;
    int m0 = blockIdx.x * 128 + w * 32;

    // A fragments straight from global: lane lr=row-in-tile, lg=k-group
    bf16x8 afr[2][4];
#pragma unroll
    for (int t = 0; t < 2; ++t) {
        int row = m0 + t * 16 + lr;
        if (row >= NN) row = NN - 1;
        const uint4* hp = (const uint4*)(H + (size_t)row * 128);
#pragma unroll
        for (int kk = 0; kk < 4; ++kk) afr[t][kk] = __builtin_bit_cast(bf16x8, hp[kk * 4 + lg]);
    }

    f32x4 acc[2][8];
#pragma unroll
    for (int t = 0; t < 2; ++t)
#pragma unroll
        for (int n = 0; n < 8; ++n) acc[t][n] = (f32x4){0.f, 0.f, 0.f, 0.f};

    int swz = (lr & 7) << 4;
    const char* Wb = (const char*)Wl;
#pragma unroll
    for (int kk = 0; kk < 4; ++kk) {
        bf16x8 bfr[8];
#pragma unroll
        for (int n = 0; n < 8; ++n) {
            int off = ((n * 16 + lr) << 8) + (((kk << 6) + (lg << 4)) ^ swz);
            bfr[n] = *(const bf16x8*)(Wb + off);
        }
#pragma unroll
        for (int n = 0; n < 8; ++n) {
            acc[0][n] = __builtin_amdgcn_mfma_f32_16x16x32_bf16(afr[0][kk], bfr[n], acc[0][n], 0, 0, 0);
            acc[1][n] = __builtin_amdgcn_mfma_f32_16x16x32_bf16(afr[1][kk], bfr[n], acc[1][n], 0, 0, 0);
        }
    }
    __syncthreads();  // everyone done reading Wl; reuse as output stage

    unsigned short* Ol = Wl;
    float bb[8];
#pragma unroll
    for (int n = 0; n < 8; ++n) bb[n] = bias[n * 16 + lr];

#pragma unroll
    for (int t = 0; t < 2; ++t) {
#pragma unroll
        for (int n = 0; n < 8; ++n) {
            int col = n * 16 + lr;
            float s = 0.f, q = 0.f;
#pragma unroll
            for (int r = 0; r < 4; ++r) {
                int lrow = w * 32 + t * 16 + lg * 4 + r;
                float v = acc[t][n][r] + bb[n];
                if (RELU) v = fmaxf(v, 0.f);
                if (STATS) {
                    bool valid = (blockIdx.x * 128 + lrow) < NN;
                    float vv = valid ? v : 0.f;
                    s += vv;
                    q += vv * vv;
                }
                int boff = lrow * 256 + ((col * 2) ^ ((lrow & 7) << 4));
                *(unsigned short*)((char*)Ol + boff) = f2bf(v);
            }
            if (STATS) { atomicAdd(&lsum[col], s); atomicAdd(&lsq[col], q); }
        }
    }
    __syncthreads();

    int mb = blockIdx.x * 128;
#pragma unroll
    for (int i = 0; i < 8; ++i) {
        int ci = tid + 256 * i;  // 0..2047 chunks of 16B
        int lrow = ci >> 4, jj = ci & 15;
        int grow = mb + lrow;
        if (grow < NN) {
            uint4 vv = *(const uint4*)((const char*)Ol + lrow * 256 + ((jj * 16) ^ ((lrow & 7) << 4)));
            ((uint4*)(C + (size_t)grow * 128))[jj] = vv;
        }
    }
    if (STATS && tid < 128) {
        atomicAdd(&gsum[tid], lsum[tid]);
        atomicAdd(&gsq[tid], lsq[tid]);
    }
}

// ---------------- BN apply + ReLU (bf16 in place) ----------------
__global__ __launch_bounds__(256) void k_bnrelu(unsigned short* __restrict__ H,
                                                const float* __restrict__ gsum, const float* __restrict__ gsq,
                                                const float* __restrict__ gamma, const float* __restrict__ beta) {
    int i = blockIdx.x * 256 + threadIdx.x;  // uint4 index, NN*16 total
    if (i >= NN * 16) return;
    int cb = (i & 15) * 8;
    uint4 v = ((uint4*)H)[i];
    float sc[8], sh[8];
    const float inv = 1.0f / (float)NN;
#pragma unroll
    for (int j = 0; j < 8; ++j) {
        float mu = gsum[cb + j] * inv;
        float var = gsq[cb + j] * inv - mu * mu;
        float s = gamma[cb + j] * rsqrtf(var + BN_EPS);
        sc[j] = s;
        sh[j] = beta[cb + j] - mu * s;
    }
    auto proc = [&](unsigned int u, int j) -> unsigned int {
        float a = fmaxf(bflo(u) * sc[j] + sh[j], 0.f);
        float b = fmaxf(bfhi(u) * sc[j + 1] + sh[j + 1], 0.f);
        return (unsigned int)f2bf(a) | ((unsigned int)f2bf(b) << 16);
    };
    v.x = proc(v.x, 0);
    v.y = proc(v.y, 2);
    v.z = proc(v.z, 4);
    v.w = proc(v.w, 6);
    ((uint4*)H)[i] = v;
}

// ---------------- per-graph mean pool (bf16 in, fp32 out) ----------------
__global__ __launch_bounds__(256) void k_pool(const unsigned short* __restrict__ X, const int* __restrict__ starts,
                                              float* __restrict__ pooled) {
    int g = blockIdx.x;
    int s = starts[g], e = starts[g + 1];
    int w = threadIdx.x >> 6, lane = threadIdx.x & 63;
    const unsigned int* x1 = (const unsigned int*)X;
    float ax = 0.f, ay = 0.f;
    for (int r = s + w; r < e; r += 4) {
        unsigned int u = x1[(size_t)r * 64 + lane];
        ax += bflo(u);
        ay += bfhi(u);
    }
    __shared__ float red[2][4][64];
    red[0][w][lane] = ax;
    red[1][w][lane] = ay;
    __syncthreads();
    if (w == 0) {
        float cnt = (float)((e - s) > 0 ? (e - s) : 1);
        float ox = (red[0][0][lane] + red[0][1][lane] + red[0][2][lane] + red[0][3][lane]) / cnt;
        float oy = (red[1][0][lane] + red[1][1][lane] + red[1][2][lane] + red[1][3][lane]) / cnt;
        float2 o = {ox, oy};
        ((float2*)pooled)[(size_t)g * 64 + lane] = o;
    }
}

// ---------------- final linear ----------------
__global__ __launch_bounds__(64) void k_final(const float* __restrict__ pooled, const float* __restrict__ lw,
                                              const float* __restrict__ lb, float* __restrict__ out) {
    int g = blockIdx.x, o = threadIdx.x;
    float acc = lb[o];
    const float* p = &pooled[(size_t)g * 128];
#pragma unroll 8
    for (int k = 0; k < 128; ++k) acc = fmaf(p[k], lw[k * 64 + o], acc);
    out[(size_t)g * 64 + o] = acc;
}

extern "C" void kernel_launch(void* const* d_in, const int* in_sizes, int n_in,
                              void* d_out, int out_size, void* d_ws, size_t ws_size,
                              hipStream_t stream) {
    const float* x = (const float*)d_in[0];
    const int* ei = (const int*)d_in[1];
    const int* src = ei;
    const int* dst = ei + NE;
    const int* batch = (const int*)d_in[2];
    const float* W1 = (const float*)d_in[3];
    const float* b1 = (const float*)d_in[4];
    const float* W2 = (const float*)d_in[5];
    const float* b2 = (const float*)d_in[6];
    const float* gamma = (const float*)d_in[7];
    const float* beta = (const float*)d_in[8];
    const float* lw = (const float*)d_in[9];
    const float* lb = (const float*)d_in[10];
    float* out = (float*)d_out;

    char* p = (char*)d_ws;
    auto alloc = [&](size_t bytes) {
        char* r = p;
        p += (bytes + 511) & ~(size_t)511;
        return r;
    };
    unsigned short* xb = (unsigned short*)alloc((size_t)NN * DIM * 2);
    unsigned short* A = (unsigned short*)alloc((size_t)NN * DIM * 2);
    unsigned short* B = (unsigned short*)alloc((size_t)NN * DIM * 2);
    unsigned short* Cb = (unsigned short*)alloc((size_t)NN * DIM * 2);
    unsigned short* Wt = (unsigned short*)alloc((size_t)6 * 16384 * 2);
    int* srcs = (int*)alloc((size_t)NE * 4);
    int* off = (int*)alloc((size_t)(NN + 1) * 4);
    int* cursor = (int*)alloc((size_t)(NN + 1) * 4);
    int* bsum = (int*)alloc(128 * 4);
    int* boff = (int*)alloc(128 * 4);
    float* gsum = (float*)alloc(DIM * 4);
    float* gsq = (float*)alloc(DIM * 4);
    int* starts = (int*)alloc((NG + 1) * 4);
    float* pooled = (float*)alloc((size_t)NG * DIM * 4);

    // ---- CSR build
    hipMemsetAsync(cursor, 0, (size_t)NN * 4, stream);
    k_hist<<<NE / 256, 256, 0, stream>>>(dst, cursor);
    int nb = (NN + SCAN_CHUNK - 1) / SCAN_CHUNK;
    k_scan1<<<nb, 256, 0, stream>>>(cursor, bsum);
    k_scan2<<<1, 1, 0, stream>>>(bsum, boff, nb, off + NN);
    k_scan3<<<nb, 256, 0, stream>>>(cursor, boff, off);
    hipMemcpyAsync(cursor, off, (size_t)NN * 4, hipMemcpyDeviceToDevice, stream);
    k_scatter<<<NE / 256, 256, 0, stream>>>(src, dst, cursor, srcs);
    k_starts<<<(NG + 1 + 255) / 256, 256, 0, stream>>>(batch, starts);

    // ---- prep: bf16 conversions
    k_prep_x<<<NN * 16 / 256, 256, 0, stream>>>(x, xb);
    k_prep_w<<<(6 * 16384) / 256, 256, 0, stream>>>(W1, W2, Wt);

    // ---- 3 GIN layers (bf16 features)
    const unsigned short* xin[3] = {xb, A, B};
    unsigned short* h0b[3] = {A, B, A};
    unsigned short* h1b[3] = {B, Cb, Cb};
    unsigned short* h2b[3] = {A, B, A};
    int gemm_grid = (NN + 127) / 128;
    for (int l = 0; l < NLAYER; ++l) {
        hipMemsetAsync(gsum, 0, DIM * 4, stream);
        hipMemsetAsync(gsq, 0, DIM * 4, stream);
        k_agg<<<NN / 4, 256, 0, stream>>>(xin[l], off, srcs, h0b[l]);
        k_gemm<1, 0><<<gemm_grid, 256, 0, stream>>>(h0b[l], Wt + (size_t)l * 16384, b1 + l * DIM, h1b[l], nullptr, nullptr);
        k_gemm<0, 1><<<gemm_grid, 256, 0, stream>>>(h1b[l], Wt + (size_t)(3 + l) * 16384, b2 + l * DIM, h2b[l], gsum, gsq);
        k_bnrelu<<<NN * 16 / 256, 256, 0, stream>>>(h2b[l], gsum, gsq, gamma + l * DIM, beta + l * DIM);
    }

    // ---- pool + final linear
    k_pool<<<NG, 256, 0, stream>>>(h2b[2], starts, pooled);
    k_final<<<NG, 64, 0, stream>>>(pooled, lw, lb, out);
}

// Round 3
// 1166.705 us; speedup vs baseline: 1.3699x; 1.0410x over previous
//
#include <hip/hip_runtime.h>

#define NN 100000
#define NE 3200000
#define NG 1000
#define DIM 128
#define OUTD 64
#define NLAYER 3
#define BN_EPS 1e-5f

#define NBUCK 1563            // ceil(NN/64)
#define NB8 (NBUCK * 8)       // (bucket, part) counters

typedef __attribute__((ext_vector_type(8))) short bf16x8;
typedef __attribute__((ext_vector_type(4))) float f32x4;

__device__ __forceinline__ float bflo(unsigned int u) { return __builtin_bit_cast(float, u << 16); }
__device__ __forceinline__ float bfhi(unsigned int u) { return __builtin_bit_cast(float, u & 0xffff0000u); }
__device__ __forceinline__ unsigned short f2bf(float f) {
    unsigned int x = __builtin_bit_cast(unsigned int, f);
    return (unsigned short)((x + 0x7fffu + ((x >> 16) & 1u)) >> 16);
}

// ---------------- bucketed CSR build ----------------
__global__ void k_bhist(const int* __restrict__ dst, int* __restrict__ bcnt8) {
    int e = blockIdx.x * 256 + threadIdx.x;
    if (e < NE) atomicAdd(&bcnt8[((dst[e] >> 6) << 3) + (blockIdx.x & 7)], 1);
}

// single-block scan over NB8+1 offsets; also writes off[NN]
__global__ __launch_bounds__(256) void k_bscan(const int* __restrict__ bcnt8, int* __restrict__ boff8,
                                               int* __restrict__ off) {
    __shared__ int sh[256];
    int t = threadIdx.x;
    const int C = 49;  // 256*49 = 12544 >= NB8+1
    int base = t * C;
    int s = 0;
    for (int j = 0; j < C; ++j) { int i = base + j; if (i < NB8) s += bcnt8[i]; }
    sh[t] = s;
    __syncthreads();
    for (int o = 1; o < 256; o <<= 1) {
        int v = (t >= o) ? sh[t - o] : 0;
        __syncthreads();
        sh[t] += v;
        __syncthreads();
    }
    int run = sh[t] - s;  // exclusive
    for (int j = 0; j < C; ++j) {
        int i = base + j;
        if (i <= NB8) boff8[i] = run;
        if (i < NB8) run += bcnt8[i];
    }
    if (t == 0) off[NN] = NE;
}

__global__ void k_bscatter(const int* __restrict__ src, const int* __restrict__ dst,
                           const int* __restrict__ boff8, int* __restrict__ bcur8,
                           uint2* __restrict__ bdata) {
    int e = blockIdx.x * 256 + threadIdx.x;
    if (e < NE) {
        int d = dst[e];
        int idx = ((d >> 6) << 3) + (blockIdx.x & 7);
        int pos = boff8[idx] + atomicAdd(&bcur8[idx], 1);
        uint2 v;
        v.x = (unsigned int)src[e];
        v.y = (unsigned int)d;
        bdata[pos] = v;
    }
}

// one block per bucket: per-node counts, offsets, and final CSR scatter
__global__ __launch_bounds__(256) void k_bfinal(const uint2* __restrict__ bdata, const int* __restrict__ boff8,
                                                int* __restrict__ off, int* __restrict__ srcs) {
    __shared__ int cnt64[64], off64[64], cur64[64];
    int b = blockIdx.x, tid = threadIdx.x;
    int base = boff8[b * 8];
    int end = boff8[b * 8 + 8];
    if (tid < 64) cnt64[tid] = 0;
    __syncthreads();
    for (int i = base + tid; i < end; i += 256) atomicAdd(&cnt64[bdata[i].y & 63], 1);
    __syncthreads();
    if (tid == 0) {
        int t = 0;
        for (int j = 0; j < 64; ++j) { off64[j] = t; t += cnt64[j]; }
    }
    __syncthreads();
    int n0 = b * 64;
    if (tid < 64) {
        if (n0 + tid < NN) off[n0 + tid] = base + off64[tid];
        cur64[tid] = 0;
    }
    __syncthreads();
    for (int i = base + tid; i < end; i += 256) {
        uint2 e = bdata[i];
        int loc = e.y & 63;
        int lpos = atomicAdd(&cur64[loc], 1);
        srcs[base + off64[loc] + lpos] = (int)e.x;
    }
}

__global__ void k_starts(const int* __restrict__ batch, int* __restrict__ starts) {
    int g = blockIdx.x * blockDim.x + threadIdx.x;
    if (g > NG) return;
    int lo = 0, hi = NN;
    while (lo < hi) {
        int mid = (lo + hi) >> 1;
        if (batch[mid] < g) lo = mid + 1; else hi = mid;
    }
    starts[g] = lo;
}

// ---------------- prep: fp32 -> bf16 ----------------
__global__ __launch_bounds__(256) void k_prep_x(const float* __restrict__ x, unsigned short* __restrict__ xb) {
    int i = blockIdx.x * 256 + threadIdx.x;  // uint4 out index, NN*16 total
    if (i >= NN * 16) return;
    const float4* xp = (const float4*)x;
    float4 a = xp[(size_t)i * 2], b = xp[(size_t)i * 2 + 1];
    uint4 o;
    o.x = (unsigned int)f2bf(a.x) | ((unsigned int)f2bf(a.y) << 16);
    o.y = (unsigned int)f2bf(a.z) | ((unsigned int)f2bf(a.w) << 16);
    o.z = (unsigned int)f2bf(b.x) | ((unsigned int)f2bf(b.y) << 16);
    o.w = (unsigned int)f2bf(b.z) | ((unsigned int)f2bf(b.w) << 16);
    ((uint4*)xb)[i] = o;
}

// W[k][c] fp32 -> Wt[c][k] bf16, XOR-swizzled 16B chunks (chunk ^= c&7)
__global__ __launch_bounds__(256) void k_prep_w(const float* __restrict__ W1, const float* __restrict__ W2,
                                                unsigned short* __restrict__ Wt) {
    int i = blockIdx.x * 256 + threadIdx.x;  // 6*16384
    if (i >= 6 * 16384) return;
    int w = i >> 14, r = i & 16383;
    int k = r >> 7, c = r & 127;
    const float* Ws = (w < 3) ? (W1 + (size_t)w * 16384) : (W2 + (size_t)(w - 3) * 16384);
    float v = Ws[r];
    int dst = (c << 7) + ((((k >> 3) ^ (c & 7)) << 3)) + (k & 7);
    Wt[((size_t)w << 14) + dst] = f2bf(v);
}

// ---------------- Aggregation (bf16): h0 = x + sum_{j->i} x_j ----------------
__global__ __launch_bounds__(256) void k_agg(const unsigned short* __restrict__ x, const int* __restrict__ off,
                                             const int* __restrict__ srcs, unsigned short* __restrict__ h0) {
    int wid = threadIdx.x >> 6;
    int lane = threadIdx.x & 63;
    int node = blockIdx.x * 4 + wid;
    if (node >= NN) return;
    const unsigned int* x1 = (const unsigned int*)x;
    unsigned int u = x1[(size_t)node * 64 + lane];
    float ax = bflo(u), ay = bfhi(u);
    int e = off[node], eend = off[node + 1];
    for (; e + 1 < eend; e += 2) {
        int s0 = srcs[e], s1 = srcs[e + 1];
        unsigned int u0 = x1[(size_t)s0 * 64 + lane];
        unsigned int u1 = x1[(size_t)s1 * 64 + lane];
        ax += bflo(u0) + bflo(u1);
        ay += bfhi(u0) + bfhi(u1);
    }
    if (e < eend) {
        unsigned int u0 = x1[(size_t)srcs[e] * 64 + lane];
        ax += bflo(u0);
        ay += bfhi(u0);
    }
    ((unsigned int*)h0)[(size_t)node * 64 + lane] = (unsigned int)f2bf(ax) | ((unsigned int)f2bf(ay) << 16);
}

// ---------------- MFMA bf16 GEMM: C[M,128] = H[M,128]@W[128,128] + bias ----------------
template <int RELU, int STATS>
__global__ __launch_bounds__(256) void k_gemm(const unsigned short* __restrict__ H,
                                              const unsigned short* __restrict__ Wt,
                                              const float* __restrict__ bias,
                                              unsigned short* __restrict__ C,
                                              float* __restrict__ gsum, float* __restrict__ gsq) {
    __shared__ unsigned short Wl[16384];  // 32KB swizzled Wt image; reused as output stage
    __shared__ float lsum[128], lsq[128];
    int tid = threadIdx.x;
    {
        const uint4* s4 = (const uint4*)Wt;
        uint4* d4 = (uint4*)Wl;
#pragma unroll
        for (int i = 0; i < 8; ++i) d4[tid + 256 * i] = s4[tid + 256 * i];
    }
    if (STATS && tid < 128) { lsum[tid] = 0.f; lsq[tid] = 0.f; }
    __syncthreads();

    int w = tid >> 6, l = tid & 63;
    int lr = l & 15, lg = l >> 4;
    int m0 = blockIdx.x * 128 + w * 32;

    bf16x8 afr[2][4];
#pragma unroll
    for (int t = 0; t < 2; ++t) {
        int row = m0 + t * 16 + lr;
        if (row >= NN) row = NN - 1;
        const uint4* hp = (const uint4*)(H + (size_t)row * 128);
#pragma unroll
        for (int kk = 0; kk < 4; ++kk) afr[t][kk] = __builtin_bit_cast(bf16x8, hp[kk * 4 + lg]);
    }

    f32x4 acc[2][8];
#pragma unroll
    for (int t = 0; t < 2; ++t)
#pragma unroll
        for (int n = 0; n < 8; ++n) acc[t][n] = (f32x4){0.f, 0.f, 0.f, 0.f};

    int swz = (lr & 7) << 4;
    const char* Wb = (const char*)Wl;
#pragma unroll
    for (int kk = 0; kk < 4; ++kk) {
        bf16x8 bfr[8];
#pragma unroll
        for (int n = 0; n < 8; ++n) {
            int off = ((n * 16 + lr) << 8) + (((kk << 6) + (lg << 4)) ^ swz);
            bfr[n] = *(const bf16x8*)(Wb + off);
        }
#pragma unroll
        for (int n = 0; n < 8; ++n) {
            acc[0][n] = __builtin_amdgcn_mfma_f32_16x16x32_bf16(afr[0][kk], bfr[n], acc[0][n], 0, 0, 0);
            acc[1][n] = __builtin_amdgcn_mfma_f32_16x16x32_bf16(afr[1][kk], bfr[n], acc[1][n], 0, 0, 0);
        }
    }
    __syncthreads();  // everyone done reading Wl; reuse as output stage

    unsigned short* Ol = Wl;
    float bb[8];
#pragma unroll
    for (int n = 0; n < 8; ++n) bb[n] = bias[n * 16 + lr];

#pragma unroll
    for (int t = 0; t < 2; ++t) {
#pragma unroll
        for (int n = 0; n < 8; ++n) {
            int col = n * 16 + lr;
            float s = 0.f, q = 0.f;
#pragma unroll
            for (int r = 0; r < 4; ++r) {
                int lrow = w * 32 + t * 16 + lg * 4 + r;
                float v = acc[t][n][r] + bb[n];
                if (RELU) v = fmaxf(v, 0.f);
                if (STATS) {
                    bool valid = (blockIdx.x * 128 + lrow) < NN;
                    float vv = valid ? v : 0.f;
                    s += vv;
                    q += vv * vv;
                }
                int boff = lrow * 256 + ((col * 2) ^ ((lrow & 7) << 4));
                *(unsigned short*)((char*)Ol + boff) = f2bf(v);
            }
            if (STATS) { atomicAdd(&lsum[col], s); atomicAdd(&lsq[col], q); }
        }
    }
    __syncthreads();

    int mb = blockIdx.x * 128;
#pragma unroll
    for (int i = 0; i < 8; ++i) {
        int ci = tid + 256 * i;  // 16B chunks
        int lrow = ci >> 4, jj = ci & 15;
        int grow = mb + lrow;
        if (grow < NN) {
            uint4 vv = *(const uint4*)((const char*)Ol + lrow * 256 + ((jj * 16) ^ ((lrow & 7) << 4)));
            ((uint4*)(C + (size_t)grow * 128))[jj] = vv;
        }
    }
    if (STATS && tid < 128) {
        atomicAdd(&gsum[tid], lsum[tid]);
        atomicAdd(&gsq[tid], lsq[tid]);
    }
}

// ---------------- BN apply + ReLU (bf16 in place) ----------------
__global__ __launch_bounds__(256) void k_bnrelu(unsigned short* __restrict__ H,
                                                const float* __restrict__ gsum, const float* __restrict__ gsq,
                                                const float* __restrict__ gamma, const float* __restrict__ beta) {
    int i = blockIdx.x * 256 + threadIdx.x;  // uint4 index, NN*16 total
    if (i >= NN * 16) return;
    int cb = (i & 15) * 8;
    uint4 v = ((uint4*)H)[i];
    float sc[8], sh[8];
    const float inv = 1.0f / (float)NN;
#pragma unroll
    for (int j = 0; j < 8; ++j) {
        float mu = gsum[cb + j] * inv;
        float var = gsq[cb + j] * inv - mu * mu;
        float s = gamma[cb + j] * rsqrtf(var + BN_EPS);
        sc[j] = s;
        sh[j] = beta[cb + j] - mu * s;
    }
    auto proc = [&](unsigned int u, int j) -> unsigned int {
        float a = fmaxf(bflo(u) * sc[j] + sh[j], 0.f);
        float b = fmaxf(bfhi(u) * sc[j + 1] + sh[j + 1], 0.f);
        return (unsigned int)f2bf(a) | ((unsigned int)f2bf(b) << 16);
    };
    v.x = proc(v.x, 0);
    v.y = proc(v.y, 2);
    v.z = proc(v.z, 4);
    v.w = proc(v.w, 6);
    ((uint4*)H)[i] = v;
}

// ---------------- per-graph mean pool (bf16 in, fp32 out) ----------------
__global__ __launch_bounds__(256) void k_pool(const unsigned short* __restrict__ X, const int* __restrict__ starts,
                                              float* __restrict__ pooled) {
    int g = blockIdx.x;
    int s = starts[g], e = starts[g + 1];
    int w = threadIdx.x >> 6, lane = threadIdx.x & 63;
    const unsigned int* x1 = (const unsigned int*)X;
    float ax = 0.f, ay = 0.f;
    for (int r = s + w; r < e; r += 4) {
        unsigned int u = x1[(size_t)r * 64 + lane];
        ax += bflo(u);
        ay += bfhi(u);
    }
    __shared__ float red[2][4][64];
    red[0][w][lane] = ax;
    red[1][w][lane] = ay;
    __syncthreads();
    if (w == 0) {
        float cnt = (float)((e - s) > 0 ? (e - s) : 1);
        float ox = (red[0][0][lane] + red[0][1][lane] + red[0][2][lane] + red[0][3][lane]) / cnt;
        float oy = (red[1][0][lane] + red[1][1][lane] + red[1][2][lane] + red[1][3][lane]) / cnt;
        float2 o = {ox, oy};
        ((float2*)pooled)[(size_t)g * 64 + lane] = o;
    }
}

// ---------------- final linear ----------------
__global__ __launch_bounds__(64) void k_final(const float* __restrict__ pooled, const float* __restrict__ lw,
                                              const float* __restrict__ lb, float* __restrict__ out) {
    int g = blockIdx.x, o = threadIdx.x;
    float acc = lb[o];
    const float* p = &pooled[(size_t)g * 128];
#pragma unroll 8
    for (int k = 0; k < 128; ++k) acc = fmaf(p[k], lw[k * 64 + o], acc);
    out[(size_t)g * 64 + o] = acc;
}

extern "C" void kernel_launch(void* const* d_in, const int* in_sizes, int n_in,
                              void* d_out, int out_size, void* d_ws, size_t ws_size,
                              hipStream_t stream) {
    const float* x = (const float*)d_in[0];
    const int* ei = (const int*)d_in[1];
    const int* src = ei;
    const int* dst = ei + NE;
    const int* batch = (const int*)d_in[2];
    const float* W1 = (const float*)d_in[3];
    const float* b1 = (const float*)d_in[4];
    const float* W2 = (const float*)d_in[5];
    const float* b2 = (const float*)d_in[6];
    const float* gamma = (const float*)d_in[7];
    const float* beta = (const float*)d_in[8];
    const float* lw = (const float*)d_in[9];
    const float* lb = (const float*)d_in[10];
    float* out = (float*)d_out;

    char* p = (char*)d_ws;
    auto alloc = [&](size_t bytes) {
        char* r = p;
        p += (bytes + 511) & ~(size_t)511;
        return r;
    };
    unsigned short* xb = (unsigned short*)alloc((size_t)NN * DIM * 2);
    unsigned short* A = (unsigned short*)alloc((size_t)NN * DIM * 2);
    unsigned short* B = (unsigned short*)alloc((size_t)NN * DIM * 2);
    unsigned short* Cb = (unsigned short*)alloc((size_t)NN * DIM * 2);
    unsigned short* Wt = (unsigned short*)alloc((size_t)6 * 16384 * 2);
    int* srcs = (int*)alloc((size_t)NE * 4);
    uint2* bdata = (uint2*)alloc((size_t)NE * 8);
    int* off = (int*)alloc((size_t)(NN + 1) * 4);
    int* bcnt8 = (int*)alloc((size_t)NB8 * 4);
    int* bcur8 = (int*)alloc((size_t)NB8 * 4);
    int* boff8 = (int*)alloc((size_t)(NB8 + 1) * 4);
    float* gsum = (float*)alloc(DIM * 4);
    float* gsq = (float*)alloc(DIM * 4);
    int* starts = (int*)alloc((NG + 1) * 4);
    float* pooled = (float*)alloc((size_t)NG * DIM * 4);

    // ---- bucketed CSR build
    hipMemsetAsync(bcnt8, 0, (size_t)NB8 * 4, stream);
    hipMemsetAsync(bcur8, 0, (size_t)NB8 * 4, stream);
    k_bhist<<<NE / 256, 256, 0, stream>>>(dst, bcnt8);
    k_bscan<<<1, 256, 0, stream>>>(bcnt8, boff8, off);
    k_bscatter<<<NE / 256, 256, 0, stream>>>(src, dst, boff8, bcur8, bdata);
    k_bfinal<<<NBUCK, 256, 0, stream>>>(bdata, boff8, off, srcs);
    k_starts<<<(NG + 1 + 255) / 256, 256, 0, stream>>>(batch, starts);

    // ---- prep: bf16 conversions
    k_prep_x<<<NN * 16 / 256, 256, 0, stream>>>(x, xb);
    k_prep_w<<<(6 * 16384) / 256, 256, 0, stream>>>(W1, W2, Wt);

    // ---- 3 GIN layers (bf16 features)
    const unsigned short* xin[3] = {xb, A, B};
    unsigned short* h0b[3] = {A, B, A};
    unsigned short* h1b[3] = {B, Cb, Cb};
    unsigned short* h2b[3] = {A, B, A};
    int gemm_grid = (NN + 127) / 128;
    for (int l = 0; l < NLAYER; ++l) {
        hipMemsetAsync(gsum, 0, DIM * 4, stream);
        hipMemsetAsync(gsq, 0, DIM * 4, stream);
        k_agg<<<NN / 4, 256, 0, stream>>>(xin[l], off, srcs, h0b[l]);
        k_gemm<1, 0><<<gemm_grid, 256, 0, stream>>>(h0b[l], Wt + (size_t)l * 16384, b1 + l * DIM, h1b[l], nullptr, nullptr);
        k_gemm<0, 1><<<gemm_grid, 256, 0, stream>>>(h1b[l], Wt + (size_t)(3 + l) * 16384, b2 + l * DIM, h2b[l], gsum, gsq);
        k_bnrelu<<<NN * 16 / 256, 256, 0, stream>>>(h2b[l], gsum, gsq, gamma + l * DIM, beta + l * DIM);
    }

    // ---- pool + final linear
    k_pool<<<NG, 256, 0, stream>>>(h2b[2], starts, pooled);
    k_final<<<NG, 64, 0, stream>>>(pooled, lw, lb, out);
}

// Round 4
// 971.518 us; speedup vs baseline: 1.6451x; 1.2009x over previous
//
#include <hip/hip_runtime.h>

#define NN 100000
#define NE 3200000
#define NG 1000
#define DIM 128
#define OUTD 64
#define NLAYER 3
#define BN_EPS 1e-5f

#define NBUCK 1563            // ceil(NN/64)
#define NB8 (NBUCK * 8)       // (bucket, part) counters

typedef __attribute__((ext_vector_type(8))) short bf16x8;
typedef __attribute__((ext_vector_type(4))) float f32x4;

__device__ __forceinline__ float bflo(unsigned int u) { return __builtin_bit_cast(float, u << 16); }
__device__ __forceinline__ float bfhi(unsigned int u) { return __builtin_bit_cast(float, u & 0xffff0000u); }
__device__ __forceinline__ unsigned short f2bf(float f) {
    unsigned int x = __builtin_bit_cast(unsigned int, f);
    return (unsigned short)((x + 0x7fffu + ((x >> 16) & 1u)) >> 16);
}

// ---------------- bucketed CSR build ----------------
__global__ void k_bhist(const int* __restrict__ dst, int* __restrict__ bcnt8) {
    int e = blockIdx.x * 256 + threadIdx.x;
    if (e < NE) atomicAdd(&bcnt8[((dst[e] >> 6) << 3) + (blockIdx.x & 7)], 1);
}

// single-block scan over NB8+1 offsets; also writes off[NN]
__global__ __launch_bounds__(256) void k_bscan(const int* __restrict__ bcnt8, int* __restrict__ boff8,
                                               int* __restrict__ off) {
    __shared__ int sh[256];
    int t = threadIdx.x;
    const int C = 49;  // 256*49 = 12544 >= NB8+1
    int base = t * C;
    int s = 0;
    for (int j = 0; j < C; ++j) { int i = base + j; if (i < NB8) s += bcnt8[i]; }
    sh[t] = s;
    __syncthreads();
    for (int o = 1; o < 256; o <<= 1) {
        int v = (t >= o) ? sh[t - o] : 0;
        __syncthreads();
        sh[t] += v;
        __syncthreads();
    }
    int run = sh[t] - s;  // exclusive
    for (int j = 0; j < C; ++j) {
        int i = base + j;
        if (i <= NB8) boff8[i] = run;
        if (i < NB8) run += bcnt8[i];
    }
    if (t == 0) off[NN] = NE;
}

// pack src (20 bits) | local-dst (6 bits) << 20
__global__ void k_bscatter(const int* __restrict__ src, const int* __restrict__ dst,
                           const int* __restrict__ boff8, int* __restrict__ bcur8,
                           unsigned int* __restrict__ bdata) {
    int e = blockIdx.x * 256 + threadIdx.x;
    if (e < NE) {
        int d = dst[e];
        int idx = ((d >> 6) << 3) + (blockIdx.x & 7);
        int pos = boff8[idx] + atomicAdd(&bcur8[idx], 1);
        bdata[pos] = (unsigned int)src[e] | ((unsigned int)(d & 63) << 20);
    }
}

// one block per bucket: per-node counts, offsets, and final CSR scatter
__global__ __launch_bounds__(256) void k_bfinal(const unsigned int* __restrict__ bdata, const int* __restrict__ boff8,
                                                int* __restrict__ off, int* __restrict__ srcs) {
    __shared__ int cnt64[64], off64[64], cur64[64];
    int b = blockIdx.x, tid = threadIdx.x;
    int base = boff8[b * 8];
    int end = boff8[b * 8 + 8];
    if (tid < 64) cnt64[tid] = 0;
    __syncthreads();
    for (int i = base + tid; i < end; i += 256) atomicAdd(&cnt64[bdata[i] >> 20], 1);
    __syncthreads();
    if (tid == 0) {
        int t = 0;
        for (int j = 0; j < 64; ++j) { off64[j] = t; t += cnt64[j]; }
    }
    __syncthreads();
    int n0 = b * 64;
    if (tid < 64) {
        if (n0 + tid < NN) off[n0 + tid] = base + off64[tid];
        cur64[tid] = 0;
    }
    __syncthreads();
    for (int i = base + tid; i < end; i += 256) {
        unsigned int e = bdata[i];
        int loc = e >> 20;
        int lpos = atomicAdd(&cur64[loc], 1);
        srcs[base + off64[loc] + lpos] = (int)(e & 0xFFFFFu);
    }
}

__global__ void k_starts(const int* __restrict__ batch, int* __restrict__ starts) {
    int g = blockIdx.x * blockDim.x + threadIdx.x;
    if (g > NG) return;
    int lo = 0, hi = NN;
    while (lo < hi) {
        int mid = (lo + hi) >> 1;
        if (batch[mid] < g) lo = mid + 1; else hi = mid;
    }
    starts[g] = lo;
}

// ---------------- prep: fp32 -> bf16 ----------------
__global__ __launch_bounds__(256) void k_prep_x(const float* __restrict__ x, unsigned short* __restrict__ xb) {
    int i = blockIdx.x * 256 + threadIdx.x;  // uint4 out index, NN*16 total
    if (i >= NN * 16) return;
    const float4* xp = (const float4*)x;
    float4 a = xp[(size_t)i * 2], b = xp[(size_t)i * 2 + 1];
    uint4 o;
    o.x = (unsigned int)f2bf(a.x) | ((unsigned int)f2bf(a.y) << 16);
    o.y = (unsigned int)f2bf(a.z) | ((unsigned int)f2bf(a.w) << 16);
    o.z = (unsigned int)f2bf(b.x) | ((unsigned int)f2bf(b.y) << 16);
    o.w = (unsigned int)f2bf(b.z) | ((unsigned int)f2bf(b.w) << 16);
    ((uint4*)xb)[i] = o;
}

// W[k][c] fp32 -> Wt[c][k] bf16, XOR-swizzled 16B chunks (chunk ^= c&7)
__global__ __launch_bounds__(256) void k_prep_w(const float* __restrict__ W1, const float* __restrict__ W2,
                                                unsigned short* __restrict__ Wt) {
    int i = blockIdx.x * 256 + threadIdx.x;  // 6*16384
    if (i >= 6 * 16384) return;
    int w = i >> 14, r = i & 16383;
    int k = r >> 7, c = r & 127;
    const float* Ws = (w < 3) ? (W1 + (size_t)w * 16384) : (W2 + (size_t)(w - 3) * 16384);
    float v = Ws[r];
    int dst = (c << 7) + ((((k >> 3) ^ (c & 7)) << 3)) + (k & 7);
    Wt[((size_t)w << 14) + dst] = f2bf(v);
}

// ---------------- Aggregation (bf16): h0 = x + sum_{j->i} x_j ----------------
// 8-deep ILP: int4-prefetched src indices, 8 independent row-gathers in flight,
// 32-bit voffset addressing (1 VALU per gather address).
__global__ __launch_bounds__(256) void k_agg(const unsigned short* __restrict__ x, const int* __restrict__ off,
                                             const int* __restrict__ srcs, unsigned short* __restrict__ h0) {
    int wid = threadIdx.x >> 6;
    int lane = threadIdx.x & 63;
    int node = blockIdx.x * 4 + wid;
    if (node >= NN) return;
    const unsigned int* x1 = (const unsigned int*)x;
    unsigned int u = x1[(unsigned)(node * 64 + lane)];
    float ax = bflo(u), ay = bfhi(u);
    int e = off[node], e1 = off[node + 1];

    // peel to 16B alignment of &srcs[e]
    while (e < e1 && (e & 3)) {
        unsigned int v = x1[(unsigned)(srcs[e] * 64 + lane)];
        ax += bflo(v);
        ay += bfhi(v);
        ++e;
    }

    if (e + 8 <= e1) {
        int4 sA = *(const int4*)&srcs[e];
        int4 sB = *(const int4*)&srcs[e + 4];
        while (true) {
            bool more = (e + 16 <= e1);
            int4 nA, nB;
            if (more) {
                nA = *(const int4*)&srcs[e + 8];
                nB = *(const int4*)&srcs[e + 12];
            }
            unsigned int v0 = x1[(unsigned)(sA.x * 64 + lane)];
            unsigned int v1 = x1[(unsigned)(sA.y * 64 + lane)];
            unsigned int v2 = x1[(unsigned)(sA.z * 64 + lane)];
            unsigned int v3 = x1[(unsigned)(sA.w * 64 + lane)];
            unsigned int v4 = x1[(unsigned)(sB.x * 64 + lane)];
            unsigned int v5 = x1[(unsigned)(sB.y * 64 + lane)];
            unsigned int v6 = x1[(unsigned)(sB.z * 64 + lane)];
            unsigned int v7 = x1[(unsigned)(sB.w * 64 + lane)];
            float x01 = bflo(v0) + bflo(v1), x23 = bflo(v2) + bflo(v3);
            float x45 = bflo(v4) + bflo(v5), x67 = bflo(v6) + bflo(v7);
            float y01 = bfhi(v0) + bfhi(v1), y23 = bfhi(v2) + bfhi(v3);
            float y45 = bfhi(v4) + bfhi(v5), y67 = bfhi(v6) + bfhi(v7);
            ax += (x01 + x23) + (x45 + x67);
            ay += (y01 + y23) + (y45 + y67);
            e += 8;
            if (!more) break;
            sA = nA;
            sB = nB;
        }
    }
    if (e + 4 <= e1) {
        int4 sA = *(const int4*)&srcs[e];
        unsigned int v0 = x1[(unsigned)(sA.x * 64 + lane)];
        unsigned int v1 = x1[(unsigned)(sA.y * 64 + lane)];
        unsigned int v2 = x1[(unsigned)(sA.z * 64 + lane)];
        unsigned int v3 = x1[(unsigned)(sA.w * 64 + lane)];
        ax += (bflo(v0) + bflo(v1)) + (bflo(v2) + bflo(v3));
        ay += (bfhi(v0) + bfhi(v1)) + (bfhi(v2) + bfhi(v3));
        e += 4;
    }
    while (e < e1) {
        unsigned int v = x1[(unsigned)(srcs[e] * 64 + lane)];
        ax += bflo(v);
        ay += bfhi(v);
        ++e;
    }
    ((unsigned int*)h0)[(unsigned)(node * 64 + lane)] = (unsigned int)f2bf(ax) | ((unsigned int)f2bf(ay) << 16);
}

// ---------------- MFMA bf16 GEMM: C[M,128] = H[M,128]@W[128,128] + bias ----------------
template <int RELU, int STATS>
__global__ __launch_bounds__(256) void k_gemm(const unsigned short* __restrict__ H,
                                              const unsigned short* __restrict__ Wt,
                                              const float* __restrict__ bias,
                                              unsigned short* __restrict__ C,
                                              float* __restrict__ gsum, float* __restrict__ gsq) {
    __shared__ unsigned short Wl[16384];  // 32KB swizzled Wt image; reused as output stage
    __shared__ float lsum[128], lsq[128];
    int tid = threadIdx.x;
    {
        const uint4* s4 = (const uint4*)Wt;
        uint4* d4 = (uint4*)Wl;
#pragma unroll
        for (int i = 0; i < 8; ++i) d4[tid + 256 * i] = s4[tid + 256 * i];
    }
    if (STATS && tid < 128) { lsum[tid] = 0.f; lsq[tid] = 0.f; }
    __syncthreads();

    int w = tid >> 6, l = tid & 63;
    int lr = l & 15, lg = l >> 4;
    int m0 = blockIdx.x * 128 + w * 32;

    bf16x8 afr[2][4];
#pragma unroll
    for (int t = 0; t < 2; ++t) {
        int row = m0 + t * 16 + lr;
        if (row >= NN) row = NN - 1;
        const uint4* hp = (const uint4*)(H + (size_t)row * 128);
#pragma unroll
        for (int kk = 0; kk < 4; ++kk) afr[t][kk] = __builtin_bit_cast(bf16x8, hp[kk * 4 + lg]);
    }

    f32x4 acc[2][8];
#pragma unroll
    for (int t = 0; t < 2; ++t)
#pragma unroll
        for (int n = 0; n < 8; ++n) acc[t][n] = (f32x4){0.f, 0.f, 0.f, 0.f};

    int swz = (lr & 7) << 4;
    const char* Wb = (const char*)Wl;
#pragma unroll
    for (int kk = 0; kk < 4; ++kk) {
        bf16x8 bfr[8];
#pragma unroll
        for (int n = 0; n < 8; ++n) {
            int off = ((n * 16 + lr) << 8) + (((kk << 6) + (lg << 4)) ^ swz);
            bfr[n] = *(const bf16x8*)(Wb + off);
        }
#pragma unroll
        for (int n = 0; n < 8; ++n) {
            acc[0][n] = __builtin_amdgcn_mfma_f32_16x16x32_bf16(afr[0][kk], bfr[n], acc[0][n], 0, 0, 0);
            acc[1][n] = __builtin_amdgcn_mfma_f32_16x16x32_bf16(afr[1][kk], bfr[n], acc[1][n], 0, 0, 0);
        }
    }
    __syncthreads();  // everyone done reading Wl; reuse as output stage

    unsigned short* Ol = Wl;
    float bb[8];
#pragma unroll
    for (int n = 0; n < 8; ++n) bb[n] = bias[n * 16 + lr];

#pragma unroll
    for (int t = 0; t < 2; ++t) {
#pragma unroll
        for (int n = 0; n < 8; ++n) {
            int col = n * 16 + lr;
            float s = 0.f, q = 0.f;
#pragma unroll
            for (int r = 0; r < 4; ++r) {
                int lrow = w * 32 + t * 16 + lg * 4 + r;
                float v = acc[t][n][r] + bb[n];
                if (RELU) v = fmaxf(v, 0.f);
                if (STATS) {
                    bool valid = (blockIdx.x * 128 + lrow) < NN;
                    float vv = valid ? v : 0.f;
                    s += vv;
                    q += vv * vv;
                }
                int boff = lrow * 256 + ((col * 2) ^ ((lrow & 7) << 4));
                *(unsigned short*)((char*)Ol + boff) = f2bf(v);
            }
            if (STATS) { atomicAdd(&lsum[col], s); atomicAdd(&lsq[col], q); }
        }
    }
    __syncthreads();

    int mb = blockIdx.x * 128;
#pragma unroll
    for (int i = 0; i < 8; ++i) {
        int ci = tid + 256 * i;  // 16B chunks
        int lrow = ci >> 4, jj = ci & 15;
        int grow = mb + lrow;
        if (grow < NN) {
            uint4 vv = *(const uint4*)((const char*)Ol + lrow * 256 + ((jj * 16) ^ ((lrow & 7) << 4)));
            ((uint4*)(C + (size_t)grow * 128))[jj] = vv;
        }
    }
    if (STATS && tid < 128) {
        atomicAdd(&gsum[tid], lsum[tid]);
        atomicAdd(&gsq[tid], lsq[tid]);
    }
}

// ---------------- BN apply + ReLU (bf16 in place) ----------------
__global__ __launch_bounds__(256) void k_bnrelu(unsigned short* __restrict__ H,
                                                const float* __restrict__ gsum, const float* __restrict__ gsq,
                                                const float* __restrict__ gamma, const float* __restrict__ beta) {
    int i = blockIdx.x * 256 + threadIdx.x;  // uint4 index, NN*16 total
    if (i >= NN * 16) return;
    int cb = (i & 15) * 8;
    uint4 v = ((uint4*)H)[i];
    float sc[8], sh[8];
    const float inv = 1.0f / (float)NN;
#pragma unroll
    for (int j = 0; j < 8; ++j) {
        float mu = gsum[cb + j] * inv;
        float var = gsq[cb + j] * inv - mu * mu;
        float s = gamma[cb + j] * rsqrtf(var + BN_EPS);
        sc[j] = s;
        sh[j] = beta[cb + j] - mu * s;
    }
    auto proc = [&](unsigned int u, int j) -> unsigned int {
        float a = fmaxf(bflo(u) * sc[j] + sh[j], 0.f);
        float b = fmaxf(bfhi(u) * sc[j + 1] + sh[j + 1], 0.f);
        return (unsigned int)f2bf(a) | ((unsigned int)f2bf(b) << 16);
    };
    v.x = proc(v.x, 0);
    v.y = proc(v.y, 2);
    v.z = proc(v.z, 4);
    v.w = proc(v.w, 6);
    ((uint4*)H)[i] = v;
}

// ---------------- per-graph mean pool (bf16 in, fp32 out) ----------------
__global__ __launch_bounds__(256) void k_pool(const unsigned short* __restrict__ X, const int* __restrict__ starts,
                                              float* __restrict__ pooled) {
    int g = blockIdx.x;
    int s = starts[g], e = starts[g + 1];
    int w = threadIdx.x >> 6, lane = threadIdx.x & 63;
    const unsigned int* x1 = (const unsigned int*)X;
    float ax = 0.f, ay = 0.f;
    for (int r = s + w; r < e; r += 4) {
        unsigned int u = x1[(size_t)r * 64 + lane];
        ax += bflo(u);
        ay += bfhi(u);
    }
    __shared__ float red[2][4][64];
    red[0][w][lane] = ax;
    red[1][w][lane] = ay;
    __syncthreads();
    if (w == 0) {
        float cnt = (float)((e - s) > 0 ? (e - s) : 1);
        float ox = (red[0][0][lane] + red[0][1][lane] + red[0][2][lane] + red[0][3][lane]) / cnt;
        float oy = (red[1][0][lane] + red[1][1][lane] + red[1][2][lane] + red[1][3][lane]) / cnt;
        float2 o = {ox, oy};
        ((float2*)pooled)[(size_t)g * 64 + lane] = o;
    }
}

// ---------------- final linear ----------------
__global__ __launch_bounds__(64) void k_final(const float* __restrict__ pooled, const float* __restrict__ lw,
                                              const float* __restrict__ lb, float* __restrict__ out) {
    int g = blockIdx.x, o = threadIdx.x;
    float acc = lb[o];
    const float* p = &pooled[(size_t)g * 128];
#pragma unroll 8
    for (int k = 0; k < 128; ++k) acc = fmaf(p[k], lw[k * 64 + o], acc);
    out[(size_t)g * 64 + o] = acc;
}

extern "C" void kernel_launch(void* const* d_in, const int* in_sizes, int n_in,
                              void* d_out, int out_size, void* d_ws, size_t ws_size,
                              hipStream_t stream) {
    const float* x = (const float*)d_in[0];
    const int* ei = (const int*)d_in[1];
    const int* src = ei;
    const int* dst = ei + NE;
    const int* batch = (const int*)d_in[2];
    const float* W1 = (const float*)d_in[3];
    const float* b1 = (const float*)d_in[4];
    const float* W2 = (const float*)d_in[5];
    const float* b2 = (const float*)d_in[6];
    const float* gamma = (const float*)d_in[7];
    const float* beta = (const float*)d_in[8];
    const float* lw = (const float*)d_in[9];
    const float* lb = (const float*)d_in[10];
    float* out = (float*)d_out;

    char* p = (char*)d_ws;
    auto alloc = [&](size_t bytes) {
        char* r = p;
        p += (bytes + 511) & ~(size_t)511;
        return r;
    };
    unsigned short* xb = (unsigned short*)alloc((size_t)NN * DIM * 2);
    unsigned short* A = (unsigned short*)alloc((size_t)NN * DIM * 2);
    unsigned short* B = (unsigned short*)alloc((size_t)NN * DIM * 2);
    unsigned short* Cb = (unsigned short*)alloc((size_t)NN * DIM * 2);
    unsigned short* Wt = (unsigned short*)alloc((size_t)6 * 16384 * 2);
    int* srcs = (int*)alloc((size_t)NE * 4);
    unsigned int* bdata = (unsigned int*)alloc((size_t)NE * 4);
    int* off = (int*)alloc((size_t)(NN + 1) * 4);
    int* bcnt8 = (int*)alloc((size_t)NB8 * 4);
    int* bcur8 = (int*)alloc((size_t)NB8 * 4);
    int* boff8 = (int*)alloc((size_t)(NB8 + 1) * 4);
    float* gsum = (float*)alloc(DIM * 4);
    float* gsq = (float*)alloc(DIM * 4);
    int* starts = (int*)alloc((NG + 1) * 4);
    float* pooled = (float*)alloc((size_t)NG * DIM * 4);

    // ---- bucketed CSR build
    hipMemsetAsync(bcnt8, 0, (size_t)NB8 * 4, stream);
    hipMemsetAsync(bcur8, 0, (size_t)NB8 * 4, stream);
    k_bhist<<<NE / 256, 256, 0, stream>>>(dst, bcnt8);
    k_bscan<<<1, 256, 0, stream>>>(bcnt8, boff8, off);
    k_bscatter<<<NE / 256, 256, 0, stream>>>(src, dst, boff8, bcur8, bdata);
    k_bfinal<<<NBUCK, 256, 0, stream>>>(bdata, boff8, off, srcs);
    k_starts<<<(NG + 1 + 255) / 256, 256, 0, stream>>>(batch, starts);

    // ---- prep: bf16 conversions
    k_prep_x<<<NN * 16 / 256, 256, 0, stream>>>(x, xb);
    k_prep_w<<<(6 * 16384) / 256, 256, 0, stream>>>(W1, W2, Wt);

    // ---- 3 GIN layers (bf16 features)
    const unsigned short* xin[3] = {xb, A, B};
    unsigned short* h0b[3] = {A, B, A};
    unsigned short* h1b[3] = {B, Cb, Cb};
    unsigned short* h2b[3] = {A, B, A};
    int gemm_grid = (NN + 127) / 128;
    for (int l = 0; l < NLAYER; ++l) {
        hipMemsetAsync(gsum, 0, DIM * 4, stream);
        hipMemsetAsync(gsq, 0, DIM * 4, stream);
        k_agg<<<NN / 4, 256, 0, stream>>>(xin[l], off, srcs, h0b[l]);
        k_gemm<1, 0><<<gemm_grid, 256, 0, stream>>>(h0b[l], Wt + (size_t)l * 16384, b1 + l * DIM, h1b[l], nullptr, nullptr);
        k_gemm<0, 1><<<gemm_grid, 256, 0, stream>>>(h1b[l], Wt + (size_t)(3 + l) * 16384, b2 + l * DIM, h2b[l], gsum, gsq);
        k_bnrelu<<<NN * 16 / 256, 256, 0, stream>>>(h2b[l], gsum, gsq, gamma + l * DIM, beta + l * DIM);
    }

    // ---- pool + final linear
    k_pool<<<NG, 256, 0, stream>>>(h2b[2], starts, pooled);
    k_final<<<NG, 64, 0, stream>>>(pooled, lw, lb, out);
}

// Round 5
// 689.087 us; speedup vs baseline: 2.3194x; 1.4099x over previous
//
#include <hip/hip_runtime.h>

#define NN 100000
#define NE 3200000
#define NG 1000
#define DIM 128
#define OUTD 64
#define NLAYER 3
#define BN_EPS 1e-5f

#define NBIN 196        // ceil(NN/512): bins of 512 nodes
#define CHA 16384       // edges per k_binA block

typedef __attribute__((ext_vector_type(8))) short bf16x8;
typedef __attribute__((ext_vector_type(4))) float f32x4;

__device__ __forceinline__ float bflo(unsigned int u) { return __builtin_bit_cast(float, u << 16); }
__device__ __forceinline__ float bfhi(unsigned int u) { return __builtin_bit_cast(float, u & 0xffff0000u); }
__device__ __forceinline__ unsigned short f2bf(float f) {
    unsigned int x = __builtin_bit_cast(unsigned int, f);
    return (unsigned short)((x + 0x7fffu + ((x >> 16) & 1u)) >> 16);
}

// ---------------- sorted-CSR build (two-level LDS binning) ----------------
__global__ __launch_bounds__(1024) void k_cnt196(const int* __restrict__ dst, int* __restrict__ gcnt) {
    __shared__ int cnt[NBIN];
    int t = threadIdx.x;
    if (t < NBIN) cnt[t] = 0;
    __syncthreads();
    int base = blockIdx.x * 8192;
#pragma unroll
    for (int i = 0; i < 8; ++i) {
        int e = base + i * 1024 + t;
        if (e < NE) atomicAdd(&cnt[dst[e] >> 9], 1);
    }
    __syncthreads();
    if (t < NBIN && cnt[t]) atomicAdd(&gcnt[t], cnt[t]);
}

__global__ void k_scan196(const int* __restrict__ gcnt, int* __restrict__ gbase, int* __restrict__ gcur,
                          int* __restrict__ off) {
    if (threadIdx.x == 0) {
        int run = 0;
        for (int i = 0; i < NBIN; ++i) {
            gbase[i] = run;
            gcur[i] = run;
            run += gcnt[i];
        }
        gbase[NBIN] = run;
        off[NN] = NE;
    }
}

// 196 blocks; per-block group-claimed contiguous writes
__global__ __launch_bounds__(1024) void k_binA(const int* __restrict__ src, const int* __restrict__ dst,
                                               int* __restrict__ gcur, unsigned int* __restrict__ bdata) {
    __shared__ int cnt[NBIN], cur[NBIN], goff[NBIN];
    __shared__ int sc[256];
    int t = threadIdx.x;
    if (t < NBIN) { cnt[t] = 0; cur[t] = 0; }
    __syncthreads();
    int base = blockIdx.x * CHA;
#pragma unroll
    for (int i = 0; i < 16; ++i) {
        int e = base + i * 1024 + t;
        if (e < NE) atomicAdd(&cnt[dst[e] >> 9], 1);
    }
    __syncthreads();
    // exclusive scan of cnt[196] (Hillis-Steele over 256)
    if (t < 256) sc[t] = (t < NBIN) ? cnt[t] : 0;
    __syncthreads();
    for (int o = 1; o < 256; o <<= 1) {
        int v = 0;
        if (t < 256 && t >= o) v = sc[t - o];
        __syncthreads();
        if (t < 256) sc[t] += v;
        __syncthreads();
    }
    if (t < NBIN && cnt[t]) goff[t] = atomicAdd(&gcur[t], cnt[t]);
    __syncthreads();
#pragma unroll
    for (int i = 0; i < 16; ++i) {
        int e = base + i * 1024 + t;
        if (e < NE) {
            int d = dst[e];
            int bin = d >> 9;
            int pos = goff[bin] + atomicAdd(&cur[bin], 1);
            bdata[pos] = ((unsigned int)src[e] << 9) | (unsigned int)(d & 511);
        }
    }
}

// one block per 512-node bucket: emits off[] and final srcs
__global__ __launch_bounds__(512) void k_binB(const unsigned int* __restrict__ bdata, const int* __restrict__ gbase,
                                              int* __restrict__ off, int* __restrict__ srcs) {
    __shared__ int cnt[512], cur[512], sc[512];
    int b = blockIdx.x, t = threadIdx.x;
    int beg = gbase[b], end = gbase[b + 1];
    cnt[t] = 0;
    cur[t] = 0;
    __syncthreads();
    for (int e = beg + t; e < end; e += 512) atomicAdd(&cnt[bdata[e] & 511], 1);
    __syncthreads();
    sc[t] = cnt[t];
    __syncthreads();
    for (int o = 1; o < 512; o <<= 1) {
        int v = (t >= o) ? sc[t - o] : 0;
        __syncthreads();
        sc[t] += v;
        __syncthreads();
    }
    int excl = sc[t] - cnt[t];
    int n = b * 512 + t;
    if (n < NN) off[n] = beg + excl;
    sc[t] = excl;  // reuse as base table
    __syncthreads();
    for (int e = beg + t; e < end; e += 512) {
        unsigned int v = bdata[e];
        int loc = v & 511;
        int pos = sc[loc] + atomicAdd(&cur[loc], 1);
        srcs[beg + pos] = (int)(v >> 9);
    }
}

__global__ void k_starts(const int* __restrict__ batch, int* __restrict__ starts) {
    int g = blockIdx.x * blockDim.x + threadIdx.x;
    if (g > NG) return;
    int lo = 0, hi = NN;
    while (lo < hi) {
        int mid = (lo + hi) >> 1;
        if (batch[mid] < g) lo = mid + 1; else hi = mid;
    }
    starts[g] = lo;
}

// ---------------- prep: fp32 -> bf16 ----------------
__global__ __launch_bounds__(256) void k_prep_x(const float* __restrict__ x, unsigned short* __restrict__ xb) {
    int i = blockIdx.x * 256 + threadIdx.x;  // uint4 out index, NN*16 total
    if (i >= NN * 16) return;
    const float4* xp = (const float4*)x;
    float4 a = xp[(size_t)i * 2], b = xp[(size_t)i * 2 + 1];
    uint4 o;
    o.x = (unsigned int)f2bf(a.x) | ((unsigned int)f2bf(a.y) << 16);
    o.y = (unsigned int)f2bf(a.z) | ((unsigned int)f2bf(a.w) << 16);
    o.z = (unsigned int)f2bf(b.x) | ((unsigned int)f2bf(b.y) << 16);
    o.w = (unsigned int)f2bf(b.z) | ((unsigned int)f2bf(b.w) << 16);
    ((uint4*)xb)[i] = o;
}

// W[k][c] fp32 -> Wt[c][k] bf16, XOR-swizzled 16B chunks (chunk ^= c&7)
__global__ __launch_bounds__(256) void k_prep_w(const float* __restrict__ W1, const float* __restrict__ W2,
                                                unsigned short* __restrict__ Wt) {
    int i = blockIdx.x * 256 + threadIdx.x;  // 6*16384
    if (i >= 6 * 16384) return;
    int w = i >> 14, r = i & 16383;
    int k = r >> 7, c = r & 127;
    const float* Ws = (w < 3) ? (W1 + (size_t)w * 16384) : (W2 + (size_t)(w - 3) * 16384);
    float v = Ws[r];
    int dst = (c << 7) + ((((k >> 3) ^ (c & 7)) << 3)) + (k & 7);
    Wt[((size_t)w << 14) + dst] = f2bf(v);
}

// ---------------- Aggregation (bf16): h0 = x + sum_{j->i} x_j ----------------
__global__ __launch_bounds__(256) void k_agg(const unsigned short* __restrict__ x, const int* __restrict__ off,
                                             const int* __restrict__ srcs, unsigned short* __restrict__ h0) {
    int wid = threadIdx.x >> 6;
    int lane = threadIdx.x & 63;
    int node = blockIdx.x * 4 + wid;
    if (node >= NN) return;
    const unsigned int* x1 = (const unsigned int*)x;
    unsigned int u = x1[(unsigned)(node * 64 + lane)];
    float ax = bflo(u), ay = bfhi(u);
    int e = off[node], e1 = off[node + 1];

    while (e < e1 && (e & 3)) {
        unsigned int v = x1[(unsigned)(srcs[e] * 64 + lane)];
        ax += bflo(v);
        ay += bfhi(v);
        ++e;
    }

    if (e + 8 <= e1) {
        int4 sA = *(const int4*)&srcs[e];
        int4 sB = *(const int4*)&srcs[e + 4];
        while (true) {
            bool more = (e + 16 <= e1);
            int4 nA, nB;
            if (more) {
                nA = *(const int4*)&srcs[e + 8];
                nB = *(const int4*)&srcs[e + 12];
            }
            unsigned int v0 = x1[(unsigned)(sA.x * 64 + lane)];
            unsigned int v1 = x1[(unsigned)(sA.y * 64 + lane)];
            unsigned int v2 = x1[(unsigned)(sA.z * 64 + lane)];
            unsigned int v3 = x1[(unsigned)(sA.w * 64 + lane)];
            unsigned int v4 = x1[(unsigned)(sB.x * 64 + lane)];
            unsigned int v5 = x1[(unsigned)(sB.y * 64 + lane)];
            unsigned int v6 = x1[(unsigned)(sB.z * 64 + lane)];
            unsigned int v7 = x1[(unsigned)(sB.w * 64 + lane)];
            float x01 = bflo(v0) + bflo(v1), x23 = bflo(v2) + bflo(v3);
            float x45 = bflo(v4) + bflo(v5), x67 = bflo(v6) + bflo(v7);
            float y01 = bfhi(v0) + bfhi(v1), y23 = bfhi(v2) + bfhi(v3);
            float y45 = bfhi(v4) + bfhi(v5), y67 = bfhi(v6) + bfhi(v7);
            ax += (x01 + x23) + (x45 + x67);
            ay += (y01 + y23) + (y45 + y67);
            e += 8;
            if (!more) break;
            sA = nA;
            sB = nB;
        }
    }
    if (e + 4 <= e1) {
        int4 sA = *(const int4*)&srcs[e];
        unsigned int v0 = x1[(unsigned)(sA.x * 64 + lane)];
        unsigned int v1 = x1[(unsigned)(sA.y * 64 + lane)];
        unsigned int v2 = x1[(unsigned)(sA.z * 64 + lane)];
        unsigned int v3 = x1[(unsigned)(sA.w * 64 + lane)];
        ax += (bflo(v0) + bflo(v1)) + (bflo(v2) + bflo(v3));
        ay += (bfhi(v0) + bfhi(v1)) + (bfhi(v2) + bfhi(v3));
        e += 4;
    }
    while (e < e1) {
        unsigned int v = x1[(unsigned)(srcs[e] * 64 + lane)];
        ax += bflo(v);
        ay += bfhi(v);
        ++e;
    }
    ((unsigned int*)h0)[(unsigned)(node * 64 + lane)] = (unsigned int)f2bf(ax) | ((unsigned int)f2bf(ay) << 16);
}

// ---------------- MFMA bf16 GEMM: C[M,128] = H[M,128]@W[128,128] + bias ----------------
template <int RELU, int STATS>
__global__ __launch_bounds__(256) void k_gemm(const unsigned short* __restrict__ H,
                                              const unsigned short* __restrict__ Wt,
                                              const float* __restrict__ bias,
                                              unsigned short* __restrict__ C,
                                              float* __restrict__ gsum, float* __restrict__ gsq) {
    __shared__ unsigned short Wl[16384];  // 32KB swizzled Wt image; reused as output stage
    __shared__ float lsum[128], lsq[128];
    int tid = threadIdx.x;
    {
        const uint4* s4 = (const uint4*)Wt;
        uint4* d4 = (uint4*)Wl;
#pragma unroll
        for (int i = 0; i < 8; ++i) d4[tid + 256 * i] = s4[tid + 256 * i];
    }
    if (STATS && tid < 128) { lsum[tid] = 0.f; lsq[tid] = 0.f; }
    __syncthreads();

    int w = tid >> 6, l = tid & 63;
    int lr = l & 15, lg = l >> 4;
    int m0 = blockIdx.x * 128 + w * 32;

    bf16x8 afr[2][4];
#pragma unroll
    for (int t = 0; t < 2; ++t) {
        int row = m0 + t * 16 + lr;
        if (row >= NN) row = NN - 1;
        const uint4* hp = (const uint4*)(H + (size_t)row * 128);
#pragma unroll
        for (int kk = 0; kk < 4; ++kk) afr[t][kk] = __builtin_bit_cast(bf16x8, hp[kk * 4 + lg]);
    }

    f32x4 acc[2][8];
#pragma unroll
    for (int t = 0; t < 2; ++t)
#pragma unroll
        for (int n = 0; n < 8; ++n) acc[t][n] = (f32x4){0.f, 0.f, 0.f, 0.f};

    int swz = (lr & 7) << 4;
    const char* Wb = (const char*)Wl;
#pragma unroll
    for (int kk = 0; kk < 4; ++kk) {
        bf16x8 bfr[8];
#pragma unroll
        for (int n = 0; n < 8; ++n) {
            int off = ((n * 16 + lr) << 8) + (((kk << 6) + (lg << 4)) ^ swz);
            bfr[n] = *(const bf16x8*)(Wb + off);
        }
#pragma unroll
        for (int n = 0; n < 8; ++n) {
            acc[0][n] = __builtin_amdgcn_mfma_f32_16x16x32_bf16(afr[0][kk], bfr[n], acc[0][n], 0, 0, 0);
            acc[1][n] = __builtin_amdgcn_mfma_f32_16x16x32_bf16(afr[1][kk], bfr[n], acc[1][n], 0, 0, 0);
        }
    }
    __syncthreads();  // everyone done reading Wl; reuse as output stage

    unsigned short* Ol = Wl;
    float bb[8];
#pragma unroll
    for (int n = 0; n < 8; ++n) bb[n] = bias[n * 16 + lr];

#pragma unroll
    for (int t = 0; t < 2; ++t) {
#pragma unroll
        for (int n = 0; n < 8; ++n) {
            int col = n * 16 + lr;
            float s = 0.f, q = 0.f;
#pragma unroll
            for (int r = 0; r < 4; ++r) {
                int lrow = w * 32 + t * 16 + lg * 4 + r;
                float v = acc[t][n][r] + bb[n];
                if (RELU) v = fmaxf(v, 0.f);
                if (STATS) {
                    bool valid = (blockIdx.x * 128 + lrow) < NN;
                    float vv = valid ? v : 0.f;
                    s += vv;
                    q += vv * vv;
                }
                int boff = lrow * 256 + ((col * 2) ^ ((lrow & 7) << 4));
                *(unsigned short*)((char*)Ol + boff) = f2bf(v);
            }
            if (STATS) { atomicAdd(&lsum[col], s); atomicAdd(&lsq[col], q); }
        }
    }
    __syncthreads();

    int mb = blockIdx.x * 128;
#pragma unroll
    for (int i = 0; i < 8; ++i) {
        int ci = tid + 256 * i;  // 16B chunks
        int lrow = ci >> 4, jj = ci & 15;
        int grow = mb + lrow;
        if (grow < NN) {
            uint4 vv = *(const uint4*)((const char*)Ol + lrow * 256 + ((jj * 16) ^ ((lrow & 7) << 4)));
            ((uint4*)(C + (size_t)grow * 128))[jj] = vv;
        }
    }
    if (STATS && tid < 128) {
        atomicAdd(&gsum[tid], lsum[tid]);
        atomicAdd(&gsq[tid], lsq[tid]);
    }
}

// ---------------- BN apply + ReLU (bf16 in place) ----------------
__global__ __launch_bounds__(256) void k_bnrelu(unsigned short* __restrict__ H,
                                                const float* __restrict__ gsum, const float* __restrict__ gsq,
                                                const float* __restrict__ gamma, const float* __restrict__ beta) {
    int i = blockIdx.x * 256 + threadIdx.x;  // uint4 index, NN*16 total
    if (i >= NN * 16) return;
    int cb = (i & 15) * 8;
    uint4 v = ((uint4*)H)[i];
    float sc[8], sh[8];
    const float inv = 1.0f / (float)NN;
#pragma unroll
    for (int j = 0; j < 8; ++j) {
        float mu = gsum[cb + j] * inv;
        float var = gsq[cb + j] * inv - mu * mu;
        float s = gamma[cb + j] * rsqrtf(var + BN_EPS);
        sc[j] = s;
        sh[j] = beta[cb + j] - mu * s;
    }
    auto proc = [&](unsigned int u, int j) -> unsigned int {
        float a = fmaxf(bflo(u) * sc[j] + sh[j], 0.f);
        float b = fmaxf(bfhi(u) * sc[j + 1] + sh[j + 1], 0.f);
        return (unsigned int)f2bf(a) | ((unsigned int)f2bf(b) << 16);
    };
    v.x = proc(v.x, 0);
    v.y = proc(v.y, 2);
    v.z = proc(v.z, 4);
    v.w = proc(v.w, 6);
    ((uint4*)H)[i] = v;
}

// ---------------- per-graph mean pool (bf16 in, fp32 out) ----------------
__global__ __launch_bounds__(256) void k_pool(const unsigned short* __restrict__ X, const int* __restrict__ starts,
                                              float* __restrict__ pooled) {
    int g = blockIdx.x;
    int s = starts[g], e = starts[g + 1];
    int w = threadIdx.x >> 6, lane = threadIdx.x & 63;
    const unsigned int* x1 = (const unsigned int*)X;
    float ax = 0.f, ay = 0.f;
    for (int r = s + w; r < e; r += 4) {
        unsigned int u = x1[(size_t)r * 64 + lane];
        ax += bflo(u);
        ay += bfhi(u);
    }
    __shared__ float red[2][4][64];
    red[0][w][lane] = ax;
    red[1][w][lane] = ay;
    __syncthreads();
    if (w == 0) {
        float cnt = (float)((e - s) > 0 ? (e - s) : 1);
        float ox = (red[0][0][lane] + red[0][1][lane] + red[0][2][lane] + red[0][3][lane]) / cnt;
        float oy = (red[1][0][lane] + red[1][1][lane] + red[1][2][lane] + red[1][3][lane]) / cnt;
        float2 o = {ox, oy};
        ((float2*)pooled)[(size_t)g * 64 + lane] = o;
    }
}

// ---------------- final linear ----------------
__global__ __launch_bounds__(64) void k_final(const float* __restrict__ pooled, const float* __restrict__ lw,
                                              const float* __restrict__ lb, float* __restrict__ out) {
    int g = blockIdx.x, o = threadIdx.x;
    float acc = lb[o];
    const float* p = &pooled[(size_t)g * 128];
#pragma unroll 8
    for (int k = 0; k < 128; ++k) acc = fmaf(p[k], lw[k * 64 + o], acc);
    out[(size_t)g * 64 + o] = acc;
}

extern "C" void kernel_launch(void* const* d_in, const int* in_sizes, int n_in,
                              void* d_out, int out_size, void* d_ws, size_t ws_size,
                              hipStream_t stream) {
    const float* x = (const float*)d_in[0];
    const int* ei = (const int*)d_in[1];
    const int* src = ei;
    const int* dst = ei + NE;
    const int* batch = (const int*)d_in[2];
    const float* W1 = (const float*)d_in[3];
    const float* b1 = (const float*)d_in[4];
    const float* W2 = (const float*)d_in[5];
    const float* b2 = (const float*)d_in[6];
    const float* gamma = (const float*)d_in[7];
    const float* beta = (const float*)d_in[8];
    const float* lw = (const float*)d_in[9];
    const float* lb = (const float*)d_in[10];
    float* out = (float*)d_out;

    char* p = (char*)d_ws;
    auto alloc = [&](size_t bytes) {
        char* r = p;
        p += (bytes + 511) & ~(size_t)511;
        return r;
    };
    unsigned short* xb = (unsigned short*)alloc((size_t)NN * DIM * 2);
    unsigned short* A = (unsigned short*)alloc((size_t)NN * DIM * 2);
    unsigned short* B = (unsigned short*)alloc((size_t)NN * DIM * 2);
    unsigned short* Cb = (unsigned short*)alloc((size_t)NN * DIM * 2);
    unsigned short* Wt = (unsigned short*)alloc((size_t)6 * 16384 * 2);
    int* srcs = (int*)alloc((size_t)NE * 4);
    unsigned int* bdata = (unsigned int*)alloc((size_t)NE * 4);
    int* off = (int*)alloc((size_t)(NN + 1) * 4);
    int* gcnt = (int*)alloc(NBIN * 4);
    int* gbase = (int*)alloc((NBIN + 1) * 4);
    int* gcur = (int*)alloc(NBIN * 4);
    float* gsum = (float*)alloc(DIM * 4);
    float* gsq = (float*)alloc(DIM * 4);
    int* starts = (int*)alloc((NG + 1) * 4);
    float* pooled = (float*)alloc((size_t)NG * DIM * 4);

    // ---- sorted-CSR build
    hipMemsetAsync(gcnt, 0, NBIN * 4, stream);
    k_cnt196<<<(NE + 8191) / 8192, 1024, 0, stream>>>(dst, gcnt);
    k_scan196<<<1, 64, 0, stream>>>(gcnt, gbase, gcur, off);
    k_binA<<<(NE + CHA - 1) / CHA, 1024, 0, stream>>>(src, dst, gcur, bdata);
    k_binB<<<NBIN, 512, 0, stream>>>(bdata, gbase, off, srcs);
    k_starts<<<(NG + 1 + 255) / 256, 256, 0, stream>>>(batch, starts);

    // ---- prep: bf16 conversions
    k_prep_x<<<NN * 16 / 256, 256, 0, stream>>>(x, xb);
    k_prep_w<<<(6 * 16384) / 256, 256, 0, stream>>>(W1, W2, Wt);

    // ---- 3 GIN layers (bf16 features)
    const unsigned short* xin[3] = {xb, A, B};
    unsigned short* h0b[3] = {A, B, A};
    unsigned short* h1b[3] = {B, Cb, Cb};
    unsigned short* h2b[3] = {A, B, A};
    int gemm_grid = (NN + 127) / 128;
    for (int l = 0; l < NLAYER; ++l) {
        hipMemsetAsync(gsum, 0, DIM * 4, stream);
        hipMemsetAsync(gsq, 0, DIM * 4, stream);
        k_agg<<<NN / 4, 256, 0, stream>>>(xin[l], off, srcs, h0b[l]);
        k_gemm<1, 0><<<gemm_grid, 256, 0, stream>>>(h0b[l], Wt + (size_t)l * 16384, b1 + l * DIM, h1b[l], nullptr, nullptr);
        k_gemm<0, 1><<<gemm_grid, 256, 0, stream>>>(h1b[l], Wt + (size_t)(3 + l) * 16384, b2 + l * DIM, h2b[l], gsum, gsq);
        k_bnrelu<<<NN * 16 / 256, 256, 0, stream>>>(h2b[l], gsum, gsq, gamma + l * DIM, beta + l * DIM);
    }

    // ---- pool + final linear
    k_pool<<<NG, 256, 0, stream>>>(h2b[2], starts, pooled);
    k_final<<<NG, 64, 0, stream>>>(pooled, lw, lb, out);
}